// Round 1
// baseline (6337.855 us; speedup 1.0000x reference)
//
#include <hip/hip_runtime.h>
#include <math.h>

#define NN 50000
#define NFEAT 256
#define NHID 128
#define OUTD 64
#define NE 800000
#define NP 3

static inline int cdiv(long a, long b) { return (int)((a + b - 1) / b); }

// out[n,m] = sum_k A[n*K+k] * B[k*M+m] (+bias[m]) (act: 0 none, 2 relu)
// grid.x = NN, block = M threads. A row staged in LDS.
template <int K, int M>
__global__ void gemm_row(const float* __restrict__ A, const float* __restrict__ B,
                         const float* __restrict__ bias, float* __restrict__ out,
                         int act) {
    __shared__ float Arow[K];
    int n = blockIdx.x;
    int t = threadIdx.x;
    const float* a = A + (long)n * K;
    for (int k = t; k < K; k += M) Arow[k] = a[k];
    __syncthreads();
    float acc = bias ? bias[t] : 0.0f;
#pragma unroll 8
    for (int k = 0; k < K; ++k) acc += Arow[k] * B[k * M + t];
    if (act == 2) acc = fmaxf(acc, 0.0f);
    out[(long)n * M + t] = acc;
}

// H_col layer 1: A row = concat over planes of spec_stack[p][n][:]  (K=192, M=128), relu
__global__ void gemm_concat_row(const float* __restrict__ spec, const float* __restrict__ B,
                                const float* __restrict__ bias, float* __restrict__ out) {
    __shared__ float Arow[192];
    int n = blockIdx.x, t = threadIdx.x;  // 128 threads
    for (int k = t; k < 192; k += 128) {
        int p = k >> 6, d = k & 63;
        Arow[k] = spec[((long)p * NN + n) * OUTD + d];
    }
    __syncthreads();
    float acc = bias[t];
#pragma unroll 8
    for (int k = 0; k < 192; ++k) acc += Arow[k] * B[k * 128 + t];
    out[(long)n * 128 + t] = fmaxf(acc, 0.0f);
}

// scatter: out[rows[e]*M + m] += scale * vals[e] * Y[cols[e]*M + m]
template <int M>
__global__ void spmm_atomic(const int* __restrict__ rows, const int* __restrict__ cols,
                            const float* __restrict__ vals, const float* __restrict__ Y,
                            float* __restrict__ out, const float* __restrict__ scale_ptr,
                            int scale_idx) {
    long tid = (long)blockIdx.x * blockDim.x + threadIdx.x;
    long e = tid / M;
    int m = (int)(tid & (M - 1));
    if (e >= NE) return;
    float s = scale_ptr ? scale_ptr[scale_idx] : 1.0f;
    int r = rows[e], c = cols[e];
    float v = vals[e] * s;
    atomicAdd(&out[(long)r * M + m], v * Y[(long)c * M + m]);
}

// x[n,m] += bias[m]; act: 0 none, 1 telu
template <int M>
__global__ void bias_act(float* __restrict__ x, const float* __restrict__ bias, int act) {
    long i = (long)blockIdx.x * blockDim.x + threadIdx.x;
    if (i >= (long)NN * M) return;
    int m = (int)(i & (M - 1));
    float v = x[i] + bias[m];
    if (act == 1) v = v * tanhf(expf(v));
    x[i] = v;
}

// per-(plane,dim) column summary over N nodes: mean, max, softmax entropy
__global__ void col_summary(const float* __restrict__ spec, float* __restrict__ ps) {
    int b = blockIdx.x;             // 0..191
    int p = b >> 6, d = b & 63;
    const float* base = spec + (long)p * NN * OUTD + d;
    int t = threadIdx.x;            // 256 threads
    __shared__ float red[256];
    float mx = -INFINITY, sm = 0.f;
    for (int n = t; n < NN; n += 256) {
        float v = base[(long)n * OUTD];
        mx = fmaxf(mx, v);
        sm += v;
    }
    red[t] = mx; __syncthreads();
    for (int s = 128; s > 0; s >>= 1) { if (t < s) red[t] = fmaxf(red[t], red[t + s]); __syncthreads(); }
    float gmax = red[0]; __syncthreads();
    red[t] = sm; __syncthreads();
    for (int s = 128; s > 0; s >>= 1) { if (t < s) red[t] += red[t + s]; __syncthreads(); }
    float gsum = red[0]; __syncthreads();
    float se = 0.f;
    for (int n = t; n < NN; n += 256) se += expf(base[(long)n * OUTD] - gmax);
    red[t] = se; __syncthreads();
    for (int s = 128; s > 0; s >>= 1) { if (t < s) red[t] += red[t + s]; __syncthreads(); }
    float Z = red[0]; __syncthreads();
    float ent = 0.f;
    for (int n = t; n < NN; n += 256) {
        float pv = expf(base[(long)n * OUTD] - gmax) / Z;
        ent -= pv * logf(pv + 1e-6f);
    }
    red[t] = ent; __syncthreads();
    for (int s = 128; s > 0; s >>= 1) { if (t < s) red[t] += red[t + s]; __syncthreads(); }
    if (t == 0) {
        ps[p * 192 + d] = gsum / (float)NN;
        ps[p * 192 + 64 + d] = gmax;
        ps[p * 192 + 128 + d] = red[0];
    }
}

// tiny 3x3: sim -> T -> random walk -> w (pi) and wprob (softmax(pi))
__global__ void walk_kernel(const float* __restrict__ ps, const float* __restrict__ weight_b,
                            const float* __restrict__ tau_p, float* __restrict__ wout) {
    if (threadIdx.x != 0 || blockIdx.x != 0) return;
    float sim[3][3];
    float inv = 1.0f / (sqrtf(192.0f) * tau_p[0]);
    for (int i = 0; i < 3; ++i)
        for (int j = 0; j < 3; ++j) {
            float dotv = 0.f;
            for (int k = 0; k < 192; ++k) dotv += ps[i * 192 + k] * ps[j * 192 + k];
            sim[i][j] = dotv * inv;
        }
    float T[3][3];
    for (int i = 0; i < 3; ++i) {
        float m = fmaxf(sim[i][0], fmaxf(sim[i][1], sim[i][2]));
        float e0 = expf(sim[i][0] - m), e1 = expf(sim[i][1] - m), e2 = expf(sim[i][2] - m);
        float s = e0 + e1 + e2;
        T[i][0] = e0 / s; T[i][1] = e1 / s; T[i][2] = e2 / s;
    }
    float b0 = weight_b[0], b1 = weight_b[1], b2 = weight_b[2];
    float m = fmaxf(b0, fmaxf(b1, b2));
    float e0 = expf(b0 - m), e1 = expf(b1 - m), e2 = expf(b2 - m);
    float s = e0 + e1 + e2;
    float pi0[3] = {e0 / s, e1 / s, e2 / s};
    float pi[3] = {pi0[0], pi0[1], pi0[2]};
    for (int it = 0; it < 13; ++it) {
        float n0 = pi[0] * T[0][0] + pi[1] * T[1][0] + pi[2] * T[2][0];
        float n1 = pi[0] * T[0][1] + pi[1] * T[1][1] + pi[2] * T[2][1];
        float n2 = pi[0] * T[0][2] + pi[1] * T[1][2] + pi[2] * T[2][2];
        pi[0] = 0.2f * pi0[0] + 0.8f * n0;
        pi[1] = 0.2f * pi0[1] + 0.8f * n1;
        pi[2] = 0.2f * pi0[2] + 0.8f * n2;
    }
    wout[0] = pi[0]; wout[1] = pi[1]; wout[2] = pi[2];
    float mm = fmaxf(pi[0], fmaxf(pi[1], pi[2]));
    float f0 = expf(pi[0] - mm), f1 = expf(pi[1] - mm), f2 = expf(pi[2] - mm);
    float fs = f0 + f1 + f2;
    wout[3] = f0 / fs; wout[4] = f1 / fs; wout[5] = f2 / fs;
}

// Hraw = (U1 + Hraw_partial(U2)) / 2, in place over the Hraw output region
__global__ void hraw_final(const float* __restrict__ U1, float* __restrict__ Hraw) {
    long i = (long)blockIdx.x * blockDim.x + threadIdx.x;
    if (i >= (long)NN * OUTD) return;
    Hraw[i] = 0.5f * (U1[i] + Hraw[i]);
}

// final projection: all_feat = [wprob-mixed spec | mean shared | Hcol | Hraw] (256) @ proj_w + proj_b
__global__ void gemm_final(const float* __restrict__ spec, const float* __restrict__ shr,
                           const float* __restrict__ Hcol, const float* __restrict__ Hraw,
                           const float* __restrict__ wvec, const float* __restrict__ projW,
                           const float* __restrict__ projB, float* __restrict__ out) {
    __shared__ float Arow[256];
    int n = blockIdx.x, t = threadIdx.x;  // 64 threads
    float w0 = wvec[3], w1 = wvec[4], w2 = wvec[5];
    Arow[t] = w0 * spec[((long)0 * NN + n) * OUTD + t] +
              w1 * spec[((long)1 * NN + n) * OUTD + t] +
              w2 * spec[((long)2 * NN + n) * OUTD + t];
    Arow[64 + t] = (shr[((long)0 * NN + n) * OUTD + t] + shr[((long)1 * NN + n) * OUTD + t] +
                    shr[((long)2 * NN + n) * OUTD + t]) * (1.0f / 3.0f);
    Arow[128 + t] = Hcol[(long)n * OUTD + t];
    Arow[192 + t] = Hraw[(long)n * OUTD + t];
    __syncthreads();
    float acc = projB[t];
#pragma unroll 8
    for (int k = 0; k < 256; ++k) acc += Arow[k] * projW[k * OUTD + t];
    out[(long)n * OUTD + t] = acc;
}

extern "C" void kernel_launch(void* const* d_in, const int* in_sizes, int n_in,
                              void* d_out, int out_size, void* d_ws, size_t ws_size,
                              hipStream_t stream) {
    const float* feature   = (const float*)d_in[0];
    const int*   edge_index= (const int*)d_in[1];   // (P,2,E) int32
    const float* edge_val  = (const float*)d_in[2]; // (P,E)
    const float* spec_w1   = (const float*)d_in[3];
    const float* spec_b1   = (const float*)d_in[4];
    const float* spec_w2   = (const float*)d_in[5];
    const float* spec_b2   = (const float*)d_in[6];
    const float* shared_w1 = (const float*)d_in[7];
    const float* shared_b1 = (const float*)d_in[8];
    const float* shared_w2 = (const float*)d_in[9];
    const float* shared_b2 = (const float*)d_in[10];
    const float* weight_b  = (const float*)d_in[11];
    const float* tau       = (const float*)d_in[12];
    const float* mlp_w1    = (const float*)d_in[13];
    const float* mlp_b1    = (const float*)d_in[14];
    const float* mlp_w2    = (const float*)d_in[15];
    const float* mlp_b2    = (const float*)d_in[16];
    const float* raw_w1    = (const float*)d_in[17];
    const float* raw_b1    = (const float*)d_in[18];
    const float* raw_w2    = (const float*)d_in[19];
    const float* raw_b2    = (const float*)d_in[20];
    const float* proj_w    = (const float*)d_in[21];
    const float* proj_b    = (const float*)d_in[22];

    float* out        = (float*)d_out;
    float* spec_stack = out + (long)NN * OUTD;
    float* shr_stack  = spec_stack + 3L * NN * OUTD;
    float* Hcol       = out + 7L * NN * OUTD;
    float* Hraw       = out + 8L * NN * OUTD;

    float* ws    = (float*)d_ws;
    float* bufXW = ws;                       // NN*128
    float* bufH1 = bufXW + (long)NN * 128;   // NN*128
    float* bufB  = bufH1 + (long)NN * 128;   // NN*64
    float* bufU1 = bufB + (long)NN * OUTD;   // NN*64
    float* psBuf = bufU1 + (long)NN * OUTD;  // 576
    float* wBuf  = psBuf + 576;              // 8

    const int TB = 256;
    int g_spmm128 = cdiv((long)NE * 128, TB);
    int g_spmm64  = cdiv((long)NE * 64, TB);
    int g_ba128   = cdiv((long)NN * 128, TB);
    int g_ba64    = cdiv((long)NN * 64, TB);

    // ---- specific planes ----
    for (int p = 0; p < NP; ++p) {
        const int* rows = edge_index + ((long)p * 2 + 0) * NE;
        const int* cols = edge_index + ((long)p * 2 + 1) * NE;
        const float* vals = edge_val + (long)p * NE;
        gemm_row<256, 128><<<NN, 128, 0, stream>>>(feature, spec_w1 + (long)p * 256 * 128, nullptr, bufXW, 0);
        hipMemsetAsync(bufH1, 0, (long)NN * 128 * sizeof(float), stream);
        spmm_atomic<128><<<g_spmm128, TB, 0, stream>>>(rows, cols, vals, bufXW, bufH1, nullptr, 0);
        bias_act<128><<<g_ba128, TB, 0, stream>>>(bufH1, spec_b1 + (long)p * 128, 1);
        gemm_row<128, 64><<<NN, 64, 0, stream>>>(bufH1, spec_w2 + (long)p * 128 * 64, nullptr, bufB, 0);
        float* dst = spec_stack + (long)p * NN * OUTD;
        hipMemsetAsync(dst, 0, (long)NN * OUTD * sizeof(float), stream);
        spmm_atomic<64><<<g_spmm64, TB, 0, stream>>>(rows, cols, vals, bufB, dst, nullptr, 0);
        bias_act<64><<<g_ba64, TB, 0, stream>>>(dst, spec_b2 + (long)p * 64, 0);
    }

    // ---- shared planes (XW computed once) ----
    gemm_row<256, 128><<<NN, 128, 0, stream>>>(feature, shared_w1, nullptr, bufXW, 0);
    for (int p = 0; p < NP; ++p) {
        const int* rows = edge_index + ((long)p * 2 + 0) * NE;
        const int* cols = edge_index + ((long)p * 2 + 1) * NE;
        const float* vals = edge_val + (long)p * NE;
        hipMemsetAsync(bufH1, 0, (long)NN * 128 * sizeof(float), stream);
        spmm_atomic<128><<<g_spmm128, TB, 0, stream>>>(rows, cols, vals, bufXW, bufH1, nullptr, 0);
        bias_act<128><<<g_ba128, TB, 0, stream>>>(bufH1, shared_b1, 1);
        gemm_row<128, 64><<<NN, 64, 0, stream>>>(bufH1, shared_w2, nullptr, bufB, 0);
        float* dst = shr_stack + (long)p * NN * OUTD;
        hipMemsetAsync(dst, 0, (long)NN * OUTD * sizeof(float), stream);
        spmm_atomic<64><<<g_spmm64, TB, 0, stream>>>(rows, cols, vals, bufB, dst, nullptr, 0);
        bias_act<64><<<g_ba64, TB, 0, stream>>>(dst, shared_b2, 0);
    }

    // ---- summaries + random walk ----
    col_summary<<<192, 256, 0, stream>>>(spec_stack, psBuf);
    walk_kernel<<<1, 64, 0, stream>>>(psBuf, weight_b, tau, wBuf);

    // ---- H_col ----
    gemm_concat_row<<<NN, 128, 0, stream>>>(spec_stack, mlp_w1, mlp_b1, bufXW);
    gemm_row<128, 64><<<NN, 64, 0, stream>>>(bufXW, mlp_w2, mlp_b2, Hcol, 0);

    // ---- H_raw ----
    gemm_row<256, 64><<<NN, 64, 0, stream>>>(feature, raw_w1, nullptr, bufB, 0);
    hipMemsetAsync(bufU1, 0, (long)NN * OUTD * sizeof(float), stream);
    for (int p = 0; p < NP; ++p) {
        const int* rows = edge_index + ((long)p * 2 + 0) * NE;
        const int* cols = edge_index + ((long)p * 2 + 1) * NE;
        const float* vals = edge_val + (long)p * NE;
        spmm_atomic<64><<<g_spmm64, TB, 0, stream>>>(rows, cols, vals, bufB, bufU1, wBuf, p);
    }
    bias_act<64><<<g_ba64, TB, 0, stream>>>(bufU1, raw_b1, 0);
    gemm_row<64, 64><<<NN, 64, 0, stream>>>(bufU1, raw_w2, nullptr, bufB, 0);
    hipMemsetAsync(Hraw, 0, (long)NN * OUTD * sizeof(float), stream);
    for (int p = 0; p < NP; ++p) {
        const int* rows = edge_index + ((long)p * 2 + 0) * NE;
        const int* cols = edge_index + ((long)p * 2 + 1) * NE;
        const float* vals = edge_val + (long)p * NE;
        spmm_atomic<64><<<g_spmm64, TB, 0, stream>>>(rows, cols, vals, bufB, Hraw, wBuf, p);
    }
    bias_act<64><<<g_ba64, TB, 0, stream>>>(Hraw, raw_b2, 0);
    hraw_final<<<g_ba64, TB, 0, stream>>>(bufU1, Hraw);

    // ---- final projection ----
    gemm_final<<<NN, 64, 0, stream>>>(spec_stack, shr_stack, Hcol, Hraw, wBuf, proj_w, proj_b, out);
}

// Round 2
// 3603.249 us; speedup vs baseline: 1.7589x; 1.7589x over previous
//
#include <hip/hip_runtime.h>
#include <math.h>

#define NN 50000
#define NFEAT 256
#define NHID 128
#define OUTD 64
#define NE 800000
#define NP 3

static inline int cdiv(long a, long b) { return (int)((a + b - 1) / b); }

// ---------------- dense GEMM (row-per-block) ----------------
// out[n,m] = sum_k A[n*K+k] * B[k*M+m] (+bias) ; grid = NN, block = M
template <int K, int M>
__global__ void gemm_row(const float* __restrict__ A, const float* __restrict__ B,
                         const float* __restrict__ bias, float* __restrict__ out) {
    __shared__ float Arow[K];
    int n = blockIdx.x;
    int t = threadIdx.x;
    const float* a = A + (long)n * K;
    for (int k = t; k < K; k += M) Arow[k] = a[k];
    __syncthreads();
    float acc = bias ? bias[t] : 0.0f;
#pragma unroll 8
    for (int k = 0; k < K; ++k) acc += Arow[k] * B[k * M + t];
    out[(long)n * M + t] = acc;
}

// H_col layer 1: A row = concat over planes of spec_stack[p][n][:]  (K=192, M=128), relu
__global__ void gemm_concat_row(const float* __restrict__ spec, const float* __restrict__ B,
                                const float* __restrict__ bias, float* __restrict__ out) {
    __shared__ float Arow[192];
    int n = blockIdx.x, t = threadIdx.x;  // 128 threads
    for (int k = t; k < 192; k += 128) {
        int p = k >> 6, d = k & 63;
        Arow[k] = spec[((long)p * NN + n) * OUTD + d];
    }
    __syncthreads();
    float acc = bias[t];
#pragma unroll 8
    for (int k = 0; k < 192; ++k) acc += Arow[k] * B[k * 128 + t];
    out[(long)n * 128 + t] = fmaxf(acc, 0.0f);
}

// ---------------- CSR build (counting sort by row) ----------------
__global__ void hist_rows(const int* __restrict__ rows, int* __restrict__ cnt) {
    int e = blockIdx.x * blockDim.x + threadIdx.x;
    if (e >= NE) return;
    atomicAdd(&cnt[rows[e]], 1);
}

// single block, 1024 threads: exclusive scan of cnt[NN] -> rowptr[NN+1]
__global__ void scan_rowptr(const int* __restrict__ cnt, int* __restrict__ rowptr) {
    __shared__ int partial[1024];
    const int CH = (NN + 1023) / 1024;  // 49
    int t = threadIdx.x;
    int base = t * CH;
    int s = 0;
    for (int i = 0; i < CH; ++i) {
        int idx = base + i;
        if (idx < NN) s += cnt[idx];
    }
    partial[t] = s;
    __syncthreads();
    for (int off = 1; off < 1024; off <<= 1) {
        int v = 0;
        if (t >= off) v = partial[t - off];
        __syncthreads();
        if (t >= off) partial[t] += v;
        __syncthreads();
    }
    int run = (t == 0) ? 0 : partial[t - 1];
    for (int i = 0; i < CH; ++i) {
        int idx = base + i;
        if (idx < NN) { rowptr[idx] = run; run += cnt[idx]; }
    }
    if (t == 0) rowptr[NN] = partial[1023];
}

__global__ void scatter_edges(const int* __restrict__ rows, const int* __restrict__ cols,
                              const float* __restrict__ vals, int* __restrict__ cursor,
                              int* __restrict__ csr_col, float* __restrict__ csr_val) {
    int e = blockIdx.x * blockDim.x + threadIdx.x;
    if (e >= NE) return;
    int r = rows[e];
    int pos = atomicAdd(&cursor[r], 1);
    csr_col[pos] = cols[e];
    csr_val[pos] = vals[e];
}

// ---------------- gather SpMM (one block per row) ----------------
// out[n,t] = act( sum_e cval[e]*Y[ccol[e]*M+t] + bias[t] )   ACT: 0 none, 1 telu
template <int M, int ACT>
__global__ void spmm_csr(const int* __restrict__ rowptr, const int* __restrict__ ccol,
                         const float* __restrict__ cval, const float* __restrict__ Y,
                         const float* __restrict__ bias, float* __restrict__ out) {
    int n = blockIdx.x, t = threadIdx.x;
    int e0 = rowptr[n], e1 = rowptr[n + 1];
    float acc = bias[t];
    for (int e = e0; e < e1; ++e) {
        int c = ccol[e];
        float v = cval[e];
        acc += v * Y[(long)c * M + t];
    }
    if (ACT == 1) acc = acc * tanhf(expf(acc));
    out[(long)n * M + t] = acc;
}

// merged 3-plane spmm: out[n,t] = sum_p w[p] * spmm_p(Y)[n,t] + bias[t]
__global__ void spmm_csr_merged(const int* __restrict__ rp0, const int* __restrict__ cc0, const float* __restrict__ cv0,
                                const int* __restrict__ rp1, const int* __restrict__ cc1, const float* __restrict__ cv1,
                                const int* __restrict__ rp2, const int* __restrict__ cc2, const float* __restrict__ cv2,
                                const float* __restrict__ Y, const float* __restrict__ wvec,
                                const float* __restrict__ bias, float* __restrict__ out) {
    int n = blockIdx.x, t = threadIdx.x;  // 64 threads
    float acc = 0.0f;
    {
        float a = 0.f;
        for (int e = rp0[n]; e < rp0[n + 1]; ++e) a += cv0[e] * Y[(long)cc0[e] * OUTD + t];
        acc += wvec[0] * a;
    }
    {
        float a = 0.f;
        for (int e = rp1[n]; e < rp1[n + 1]; ++e) a += cv1[e] * Y[(long)cc1[e] * OUTD + t];
        acc += wvec[1] * a;
    }
    {
        float a = 0.f;
        for (int e = rp2[n]; e < rp2[n + 1]; ++e) a += cv2[e] * Y[(long)cc2[e] * OUTD + t];
        acc += wvec[2] * a;
    }
    out[(long)n * OUTD + t] = acc + bias[t];
}

// ---------------- summaries / walk / epilogue ----------------
__global__ void col_summary(const float* __restrict__ spec, float* __restrict__ ps) {
    int b = blockIdx.x;  // 0..191
    int p = b >> 6, d = b & 63;
    const float* base = spec + (long)p * NN * OUTD + d;
    int t = threadIdx.x;  // 256 threads
    __shared__ float red[256];
    float mx = -INFINITY, sm = 0.f;
    for (int n = t; n < NN; n += 256) {
        float v = base[(long)n * OUTD];
        mx = fmaxf(mx, v);
        sm += v;
    }
    red[t] = mx; __syncthreads();
    for (int s = 128; s > 0; s >>= 1) { if (t < s) red[t] = fmaxf(red[t], red[t + s]); __syncthreads(); }
    float gmax = red[0]; __syncthreads();
    red[t] = sm; __syncthreads();
    for (int s = 128; s > 0; s >>= 1) { if (t < s) red[t] += red[t + s]; __syncthreads(); }
    float gsum = red[0]; __syncthreads();
    float se = 0.f;
    for (int n = t; n < NN; n += 256) se += expf(base[(long)n * OUTD] - gmax);
    red[t] = se; __syncthreads();
    for (int s = 128; s > 0; s >>= 1) { if (t < s) red[t] += red[t + s]; __syncthreads(); }
    float Z = red[0]; __syncthreads();
    float ent = 0.f;
    for (int n = t; n < NN; n += 256) {
        float pv = expf(base[(long)n * OUTD] - gmax) / Z;
        ent -= pv * logf(pv + 1e-6f);
    }
    red[t] = ent; __syncthreads();
    for (int s = 128; s > 0; s >>= 1) { if (t < s) red[t] += red[t + s]; __syncthreads(); }
    if (t == 0) {
        ps[p * 192 + d] = gsum / (float)NN;
        ps[p * 192 + 64 + d] = gmax;
        ps[p * 192 + 128 + d] = red[0];
    }
}

__global__ void walk_kernel(const float* __restrict__ ps, const float* __restrict__ weight_b,
                            const float* __restrict__ tau_p, float* __restrict__ wout) {
    if (threadIdx.x != 0 || blockIdx.x != 0) return;
    float sim[3][3];
    float inv = 1.0f / (sqrtf(192.0f) * tau_p[0]);
    for (int i = 0; i < 3; ++i)
        for (int j = 0; j < 3; ++j) {
            float dotv = 0.f;
            for (int k = 0; k < 192; ++k) dotv += ps[i * 192 + k] * ps[j * 192 + k];
            sim[i][j] = dotv * inv;
        }
    float T[3][3];
    for (int i = 0; i < 3; ++i) {
        float m = fmaxf(sim[i][0], fmaxf(sim[i][1], sim[i][2]));
        float e0 = expf(sim[i][0] - m), e1 = expf(sim[i][1] - m), e2 = expf(sim[i][2] - m);
        float s = e0 + e1 + e2;
        T[i][0] = e0 / s; T[i][1] = e1 / s; T[i][2] = e2 / s;
    }
    float b0 = weight_b[0], b1 = weight_b[1], b2 = weight_b[2];
    float m = fmaxf(b0, fmaxf(b1, b2));
    float e0 = expf(b0 - m), e1 = expf(b1 - m), e2 = expf(b2 - m);
    float s = e0 + e1 + e2;
    float pi0[3] = {e0 / s, e1 / s, e2 / s};
    float pi[3] = {pi0[0], pi0[1], pi0[2]};
    for (int it = 0; it < 13; ++it) {
        float n0 = pi[0] * T[0][0] + pi[1] * T[1][0] + pi[2] * T[2][0];
        float n1 = pi[0] * T[0][1] + pi[1] * T[1][1] + pi[2] * T[2][1];
        float n2 = pi[0] * T[0][2] + pi[1] * T[1][2] + pi[2] * T[2][2];
        pi[0] = 0.2f * pi0[0] + 0.8f * n0;
        pi[1] = 0.2f * pi0[1] + 0.8f * n1;
        pi[2] = 0.2f * pi0[2] + 0.8f * n2;
    }
    wout[0] = pi[0]; wout[1] = pi[1]; wout[2] = pi[2];
    float mm = fmaxf(pi[0], fmaxf(pi[1], pi[2]));
    float f0 = expf(pi[0] - mm), f1 = expf(pi[1] - mm), f2 = expf(pi[2] - mm);
    float fs = f0 + f1 + f2;
    wout[3] = f0 / fs; wout[4] = f1 / fs; wout[5] = f2 / fs;
}

__global__ void hraw_final(const float* __restrict__ U1, float* __restrict__ Hraw) {
    long i = (long)blockIdx.x * blockDim.x + threadIdx.x;
    if (i >= (long)NN * OUTD) return;
    Hraw[i] = 0.5f * (U1[i] + Hraw[i]);
}

__global__ void gemm_final(const float* __restrict__ spec, const float* __restrict__ shr,
                           const float* __restrict__ Hcol, const float* __restrict__ Hraw,
                           const float* __restrict__ wvec, const float* __restrict__ projW,
                           const float* __restrict__ projB, float* __restrict__ out) {
    __shared__ float Arow[256];
    int n = blockIdx.x, t = threadIdx.x;  // 64 threads
    float w0 = wvec[3], w1 = wvec[4], w2 = wvec[5];
    Arow[t] = w0 * spec[((long)0 * NN + n) * OUTD + t] +
              w1 * spec[((long)1 * NN + n) * OUTD + t] +
              w2 * spec[((long)2 * NN + n) * OUTD + t];
    Arow[64 + t] = (shr[((long)0 * NN + n) * OUTD + t] + shr[((long)1 * NN + n) * OUTD + t] +
                    shr[((long)2 * NN + n) * OUTD + t]) * (1.0f / 3.0f);
    Arow[128 + t] = Hcol[(long)n * OUTD + t];
    Arow[192 + t] = Hraw[(long)n * OUTD + t];
    __syncthreads();
    float acc = projB[t];
#pragma unroll 8
    for (int k = 0; k < 256; ++k) acc += Arow[k] * projW[k * OUTD + t];
    out[(long)n * OUTD + t] = acc;
}

extern "C" void kernel_launch(void* const* d_in, const int* in_sizes, int n_in,
                              void* d_out, int out_size, void* d_ws, size_t ws_size,
                              hipStream_t stream) {
    const float* feature   = (const float*)d_in[0];
    const int*   edge_index= (const int*)d_in[1];   // (P,2,E) int32
    const float* edge_val  = (const float*)d_in[2]; // (P,E)
    const float* spec_w1   = (const float*)d_in[3];
    const float* spec_b1   = (const float*)d_in[4];
    const float* spec_w2   = (const float*)d_in[5];
    const float* spec_b2   = (const float*)d_in[6];
    const float* shared_w1 = (const float*)d_in[7];
    const float* shared_b1 = (const float*)d_in[8];
    const float* shared_w2 = (const float*)d_in[9];
    const float* shared_b2 = (const float*)d_in[10];
    const float* weight_b  = (const float*)d_in[11];
    const float* tau       = (const float*)d_in[12];
    const float* mlp_w1    = (const float*)d_in[13];
    const float* mlp_b1    = (const float*)d_in[14];
    const float* mlp_w2    = (const float*)d_in[15];
    const float* mlp_b2    = (const float*)d_in[16];
    const float* raw_w1    = (const float*)d_in[17];
    const float* raw_b1    = (const float*)d_in[18];
    const float* raw_w2    = (const float*)d_in[19];
    const float* raw_b2    = (const float*)d_in[20];
    const float* proj_w    = (const float*)d_in[21];
    const float* proj_b    = (const float*)d_in[22];

    float* out        = (float*)d_out;
    float* spec_stack = out + (long)NN * OUTD;
    float* shr_stack  = spec_stack + 3L * NN * OUTD;
    float* Hcol       = out + 7L * NN * OUTD;
    float* Hraw       = out + 8L * NN * OUTD;

    // ---- workspace carve ----
    char* wp = (char*)d_ws;
    float* bufXW = (float*)wp; wp += (long)NN * 128 * sizeof(float);
    float* bufH1 = (float*)wp; wp += (long)NN * 128 * sizeof(float);
    float* bufB  = (float*)wp; wp += (long)NN * OUTD * sizeof(float);
    float* bufU1 = (float*)wp; wp += (long)NN * OUTD * sizeof(float);
    float* psBuf = (float*)wp; wp += 1024 * sizeof(float);
    float* wBuf  = (float*)wp; wp += 64 * sizeof(float);
    int*   csr_col[NP]; float* csr_val[NP]; int* rowptr[NP];
    for (int p = 0; p < NP; ++p) {
        csr_col[p] = (int*)wp;   wp += (long)NE * sizeof(int);
        csr_val[p] = (float*)wp; wp += (long)NE * sizeof(float);
        rowptr[p]  = (int*)wp;   wp += (NN + 2) * sizeof(int);
    }
    int* cnt    = (int*)wp; wp += (long)NN * sizeof(int);
    int* cursor = (int*)wp; wp += (long)NN * sizeof(int);

    const int TB = 256;
    int g_edges = cdiv(NE, TB);

    // ---- build CSR for each plane ----
    for (int p = 0; p < NP; ++p) {
        const int* rows = edge_index + ((long)p * 2 + 0) * NE;
        const int* cols = edge_index + ((long)p * 2 + 1) * NE;
        const float* vals = edge_val + (long)p * NE;
        hipMemsetAsync(cnt, 0, NN * sizeof(int), stream);
        hist_rows<<<g_edges, TB, 0, stream>>>(rows, cnt);
        scan_rowptr<<<1, 1024, 0, stream>>>(cnt, rowptr[p]);
        hipMemcpyAsync(cursor, rowptr[p], NN * sizeof(int), hipMemcpyDeviceToDevice, stream);
        scatter_edges<<<g_edges, TB, 0, stream>>>(rows, cols, vals, cursor, csr_col[p], csr_val[p]);
    }

    // ---- specific planes ----
    for (int p = 0; p < NP; ++p) {
        gemm_row<256, 128><<<NN, 128, 0, stream>>>(feature, spec_w1 + (long)p * 256 * 128, nullptr, bufXW);
        spmm_csr<128, 1><<<NN, 128, 0, stream>>>(rowptr[p], csr_col[p], csr_val[p], bufXW,
                                                 spec_b1 + (long)p * 128, bufH1);
        gemm_row<128, 64><<<NN, 64, 0, stream>>>(bufH1, spec_w2 + (long)p * 128 * 64, nullptr, bufB);
        spmm_csr<64, 0><<<NN, 64, 0, stream>>>(rowptr[p], csr_col[p], csr_val[p], bufB,
                                               spec_b2 + (long)p * 64, spec_stack + (long)p * NN * OUTD);
    }

    // ---- shared planes (XW computed once) ----
    gemm_row<256, 128><<<NN, 128, 0, stream>>>(feature, shared_w1, nullptr, bufXW);
    for (int p = 0; p < NP; ++p) {
        spmm_csr<128, 1><<<NN, 128, 0, stream>>>(rowptr[p], csr_col[p], csr_val[p], bufXW,
                                                 shared_b1, bufH1);
        gemm_row<128, 64><<<NN, 64, 0, stream>>>(bufH1, shared_w2, nullptr, bufB);
        spmm_csr<64, 0><<<NN, 64, 0, stream>>>(rowptr[p], csr_col[p], csr_val[p], bufB,
                                               shared_b2, shr_stack + (long)p * NN * OUTD);
    }

    // ---- summaries + random walk ----
    col_summary<<<192, 256, 0, stream>>>(spec_stack, psBuf);
    walk_kernel<<<1, 64, 0, stream>>>(psBuf, weight_b, tau, wBuf);

    // ---- H_col ----
    gemm_concat_row<<<NN, 128, 0, stream>>>(spec_stack, mlp_w1, mlp_b1, bufXW);
    gemm_row<128, 64><<<NN, 64, 0, stream>>>(bufXW, mlp_w2, mlp_b2, Hcol);

    // ---- H_raw ----
    gemm_row<256, 64><<<NN, 64, 0, stream>>>(feature, raw_w1, nullptr, bufB);
    spmm_csr_merged<<<NN, 64, 0, stream>>>(rowptr[0], csr_col[0], csr_val[0],
                                           rowptr[1], csr_col[1], csr_val[1],
                                           rowptr[2], csr_col[2], csr_val[2],
                                           bufB, wBuf, raw_b1, bufU1);
    gemm_row<64, 64><<<NN, 64, 0, stream>>>(bufU1, raw_w2, nullptr, bufB);
    spmm_csr_merged<<<NN, 64, 0, stream>>>(rowptr[0], csr_col[0], csr_val[0],
                                           rowptr[1], csr_col[1], csr_val[1],
                                           rowptr[2], csr_col[2], csr_val[2],
                                           bufB, wBuf, raw_b2, Hraw);
    hraw_final<<<cdiv((long)NN * OUTD, TB), TB, 0, stream>>>(bufU1, Hraw);

    // ---- final projection ----
    gemm_final<<<NN, 64, 0, stream>>>(spec_stack, shr_stack, Hcol, Hraw, wBuf, proj_w, proj_b, out);
}

// Round 3
// 2791.943 us; speedup vs baseline: 2.2701x; 1.2906x over previous
//
#include <hip/hip_runtime.h>
#include <math.h>

#define NN 50000
#define NFEAT 256
#define NHID 128
#define OUTD 64
#define NE 800000
#define NP 3
#define NCH 64
#define RC 782  // ceil(NN/NCH)

static inline int cdiv(long a, long b) { return (int)((a + b - 1) / b); }

// =============== tiled f32 GEMM ===============
// BM=64 rows/block, BK=32, BN=M. 256 threads, thread tile 4 x TN (TN=M/16).
// MODE: 0 plain A[n*K+k] ; 1 concat3 (A=spec_stack, K=192) ; 2 mix (final all_feat, K=256)
// ACT: 0 none, 2 relu
template <int K, int M, int MODE, int ACT>
__global__ __launch_bounds__(256) void gemm_tiled(
    const float* __restrict__ A, const float* __restrict__ B,
    const float* __restrict__ bias, float* __restrict__ out, int nrows,
    const float* __restrict__ wvec, const float* __restrict__ s1,
    const float* __restrict__ s2, const float* __restrict__ s3) {
    constexpr int TN = M / 16;          // 8 for M=128, 4 for M=64
    constexpr int APAD = 68;            // LDS row stride for As (16B-aligned rows, low conflict)
    __shared__ float As[32 * APAD];     // As[k][row]
    __shared__ float Bs[32 * M];        // Bs[k][col]

    int n0 = blockIdx.x * 64;
    int t = threadIdx.x;
    int tx = t & 15, ty = t >> 4;       // col group, row group
    int col0 = tx * TN, row0 = ty * 4;

    float w0 = 0.f, w1 = 0.f, w2 = 0.f;
    if (MODE == 2) { w0 = wvec[3]; w1 = wvec[4]; w2 = wvec[5]; }

    float acc[4][TN];
#pragma unroll
    for (int i = 0; i < 4; ++i)
#pragma unroll
        for (int j = 0; j < TN; ++j) acc[i][j] = 0.f;

    int kk = t & 31, rr = t >> 5;       // A-loader: k-lane, row-lane (8 rows/pass)

    for (int k0 = 0; k0 < K; k0 += 32) {
        // ---- load A tile (64 rows x 32 k) ----
#pragma unroll
        for (int pass = 0; pass < 8; ++pass) {
            int row = rr + pass * 8;
            int gn = n0 + row;
            float v = 0.f;
            if (gn < nrows) {
                if (MODE == 0) {
                    v = A[(long)gn * K + k0 + kk];
                } else if (MODE == 1) {
                    int plane = k0 >> 6;
                    int d = (k0 & 63) + kk;
                    v = A[((long)plane * NN + gn) * OUTD + d];
                } else {
                    int seg = k0 >> 6;
                    int d = (k0 & 63) + kk;
                    if (seg == 0) {
                        v = w0 * A[((long)0 * NN + gn) * OUTD + d] +
                            w1 * A[((long)1 * NN + gn) * OUTD + d] +
                            w2 * A[((long)2 * NN + gn) * OUTD + d];
                    } else if (seg == 1) {
                        v = (s1[((long)0 * NN + gn) * OUTD + d] +
                             s1[((long)1 * NN + gn) * OUTD + d] +
                             s1[((long)2 * NN + gn) * OUTD + d]) * (1.0f / 3.0f);
                    } else if (seg == 2) {
                        v = s2[(long)gn * OUTD + d];
                    } else {
                        v = s3[(long)gn * OUTD + d];
                    }
                }
            }
            As[kk * APAD + row] = v;
        }
        // ---- load B tile (32 k x M cols) ----
#pragma unroll
        for (int i = 0; i < (32 * M) / 256; ++i) {
            int idx = i * 256 + t;
            int kr = idx / M, col = idx % M;
            Bs[kr * M + col] = B[(long)(k0 + kr) * M + col];
        }
        __syncthreads();
        // ---- compute ----
#pragma unroll 8
        for (int k = 0; k < 32; ++k) {
            float ra[4], rb[TN];
#pragma unroll
            for (int i = 0; i < 4; ++i) ra[i] = As[k * APAD + row0 + i];
#pragma unroll
            for (int j = 0; j < TN; ++j) rb[j] = Bs[k * M + col0 + j];
#pragma unroll
            for (int i = 0; i < 4; ++i)
#pragma unroll
                for (int j = 0; j < TN; ++j) acc[i][j] += ra[i] * rb[j];
        }
        __syncthreads();
    }
    // ---- epilogue ----
#pragma unroll
    for (int i = 0; i < 4; ++i) {
        int gn = n0 + row0 + i;
        if (gn >= nrows) continue;
#pragma unroll
        for (int j = 0; j < TN; ++j) {
            float v = acc[i][j] + (bias ? bias[col0 + j] : 0.f);
            if (ACT == 2) v = fmaxf(v, 0.f);
            out[(long)gn * M + col0 + j] = v;
        }
    }
}

// =============== CSR build ===============
__global__ void hist_rows(const int* __restrict__ rows, int* __restrict__ cnt) {
    int e = blockIdx.x * blockDim.x + threadIdx.x;
    if (e >= NE) return;
    atomicAdd(&cnt[rows[e]], 1);
}

__global__ void scan_rowptr(const int* __restrict__ cnt, int* __restrict__ rowptr) {
    __shared__ int partial[1024];
    const int CH = (NN + 1023) / 1024;
    int t = threadIdx.x;
    int base = t * CH;
    int s = 0;
    for (int i = 0; i < CH; ++i) {
        int idx = base + i;
        if (idx < NN) s += cnt[idx];
    }
    partial[t] = s;
    __syncthreads();
    for (int off = 1; off < 1024; off <<= 1) {
        int v = 0;
        if (t >= off) v = partial[t - off];
        __syncthreads();
        if (t >= off) partial[t] += v;
        __syncthreads();
    }
    int run = (t == 0) ? 0 : partial[t - 1];
    for (int i = 0; i < CH; ++i) {
        int idx = base + i;
        if (idx < NN) { rowptr[idx] = run; run += cnt[idx]; }
    }
    if (t == 0) rowptr[NN] = partial[1023];
}

__global__ void scatter_edges(const int* __restrict__ rows, const int* __restrict__ cols,
                              const float* __restrict__ vals, int* __restrict__ cursor,
                              int* __restrict__ csr_col, float* __restrict__ csr_val) {
    int e = blockIdx.x * blockDim.x + threadIdx.x;
    if (e >= NE) return;
    int r = rows[e];
    int pos = atomicAdd(&cursor[r], 1);
    csr_col[pos] = cols[e];
    csr_val[pos] = vals[e];
}

// =============== gather SpMM ===============
template <int M, int ACT>  // ACT: 0 none, 1 telu
__global__ void spmm_csr(const int* __restrict__ rowptr, const int* __restrict__ ccol,
                         const float* __restrict__ cval, const float* __restrict__ Y,
                         const float* __restrict__ bias, float* __restrict__ out) {
    int n = blockIdx.x, t = threadIdx.x;
    int e0 = rowptr[n], e1 = rowptr[n + 1];
    float acc = bias[t];
    for (int e = e0; e < e1; ++e) {
        int c = ccol[e];
        float v = cval[e];
        acc += v * Y[(long)c * M + t];
    }
    if (ACT == 1) acc = acc * tanhf(expf(acc));
    out[(long)n * M + t] = acc;
}

__global__ void spmm_csr_merged(const int* __restrict__ rp0, const int* __restrict__ cc0, const float* __restrict__ cv0,
                                const int* __restrict__ rp1, const int* __restrict__ cc1, const float* __restrict__ cv1,
                                const int* __restrict__ rp2, const int* __restrict__ cc2, const float* __restrict__ cv2,
                                const float* __restrict__ Y, const float* __restrict__ wvec,
                                const float* __restrict__ bias, float* __restrict__ out) {
    int n = blockIdx.x, t = threadIdx.x;  // 64 threads
    float acc = 0.0f;
    {
        float a = 0.f;
        for (int e = rp0[n]; e < rp0[n + 1]; ++e) a += cv0[e] * Y[(long)cc0[e] * OUTD + t];
        acc += wvec[0] * a;
    }
    {
        float a = 0.f;
        for (int e = rp1[n]; e < rp1[n + 1]; ++e) a += cv1[e] * Y[(long)cc1[e] * OUTD + t];
        acc += wvec[1] * a;
    }
    {
        float a = 0.f;
        for (int e = rp2[n]; e < rp2[n + 1]; ++e) a += cv2[e] * Y[(long)cc2[e] * OUTD + t];
        acc += wvec[2] * a;
    }
    out[(long)n * OUTD + t] = acc + bias[t];
}

// =============== column summaries (coalesced, chunked) ===============
// pass A: per (plane, chunk): online max/sum/expsum partials per dim
__global__ void colsum_passA(const float* __restrict__ spec, float* __restrict__ pmax,
                             float* __restrict__ psum, float* __restrict__ pexp) {
    int p = blockIdx.y, c = blockIdx.x;
    int t = threadIdx.x;
    int d = t & 63, rg = t >> 6;  // 4 row groups
    const float* base = spec + (long)p * NN * OUTD;
    int r0 = c * RC, r1 = min(r0 + RC, NN);
    float m = -INFINITY, s = 0.f, e = 0.f;
    for (int r = r0 + rg; r < r1; r += 4) {
        float v = base[(long)r * OUTD + d];
        s += v;
        if (v > m) { e = e * __expf(m - v) + 1.0f; m = v; }
        else e += __expf(v - m);
    }
    __shared__ float rm[256], rs[256], re[256];
    rm[t] = m; rs[t] = s; re[t] = e;
    __syncthreads();
    for (int off = 128; off >= 64; off >>= 1) {
        if (t < off) {
            float m2 = fmaxf(rm[t], rm[t + off]);
            re[t] = re[t] * __expf(rm[t] - m2) + re[t + off] * __expf(rm[t + off] - m2);
            rm[t] = m2;
            rs[t] = rs[t] + rs[t + off];
        }
        __syncthreads();
    }
    if (t < 64) {
        long idx = ((long)p * 64 + t) * NCH + c;
        pmax[idx] = rm[t]; psum[idx] = rs[t]; pexp[idx] = re[t];
    }
}

// reduce B: per (plane,dim): gmax, Z, mean
__global__ void colsum_reduceB(const float* __restrict__ pmax, const float* __restrict__ psum,
                               const float* __restrict__ pexp, float* __restrict__ ps,
                               float* __restrict__ zbuf) {
    int b = blockIdx.x;  // p*64+d
    int p = b >> 6, d = b & 63;
    int t = threadIdx.x;  // 64 threads = NCH
    long idx = (long)b * NCH + t;
    float m = pmax[idx], s = psum[idx], e = pexp[idx];
    for (int off = 32; off > 0; off >>= 1) {
        float m2 = fmaxf(m, __shfl_xor(m, off));
        e = e * __expf(m - m2) + __shfl_xor(e, off) * __expf(__shfl_xor(m, off) - m2);
        m = m2;
        s += __shfl_xor(s, off);
    }
    if (t == 0) {
        ps[p * 192 + d] = s / (float)NN;
        ps[p * 192 + 64 + d] = m;
        zbuf[b] = e;
    }
}

// pass C: entropy partials given gmax, Z
__global__ void colsum_passC(const float* __restrict__ spec, const float* __restrict__ ps,
                             const float* __restrict__ zbuf, float* __restrict__ pent) {
    int p = blockIdx.y, c = blockIdx.x;
    int t = threadIdx.x;
    int d = t & 63, rg = t >> 6;
    const float* base = spec + (long)p * NN * OUTD;
    float gm = ps[p * 192 + 64 + d];
    float zinv = 1.0f / zbuf[p * 64 + d];
    int r0 = c * RC, r1 = min(r0 + RC, NN);
    float ent = 0.f;
    for (int r = r0 + rg; r < r1; r += 4) {
        float v = base[(long)r * OUTD + d];
        float pv = __expf(v - gm) * zinv;
        ent -= pv * __logf(pv + 1e-6f);
    }
    __shared__ float rd[256];
    rd[t] = ent;
    __syncthreads();
    for (int off = 128; off >= 64; off >>= 1) {
        if (t < off) rd[t] += rd[t + off];
        __syncthreads();
    }
    if (t < 64) pent[((long)p * 64 + t) * NCH + c] = rd[t];
}

__global__ void colsum_reduceD(const float* __restrict__ pent, float* __restrict__ ps) {
    int b = blockIdx.x;  // p*64+d
    int p = b >> 6, d = b & 63;
    int t = threadIdx.x;  // 64
    float e = pent[(long)b * NCH + t];
    for (int off = 32; off > 0; off >>= 1) e += __shfl_xor(e, off);
    if (t == 0) ps[p * 192 + 128 + d] = e;
}

// =============== walk + epilogue ===============
__global__ void walk_kernel(const float* __restrict__ ps, const float* __restrict__ weight_b,
                            const float* __restrict__ tau_p, float* __restrict__ wout) {
    if (threadIdx.x != 0 || blockIdx.x != 0) return;
    float sim[3][3];
    float inv = 1.0f / (sqrtf(192.0f) * tau_p[0]);
    for (int i = 0; i < 3; ++i)
        for (int j = 0; j < 3; ++j) {
            float dotv = 0.f;
            for (int k = 0; k < 192; ++k) dotv += ps[i * 192 + k] * ps[j * 192 + k];
            sim[i][j] = dotv * inv;
        }
    float T[3][3];
    for (int i = 0; i < 3; ++i) {
        float m = fmaxf(sim[i][0], fmaxf(sim[i][1], sim[i][2]));
        float e0 = expf(sim[i][0] - m), e1 = expf(sim[i][1] - m), e2 = expf(sim[i][2] - m);
        float s = e0 + e1 + e2;
        T[i][0] = e0 / s; T[i][1] = e1 / s; T[i][2] = e2 / s;
    }
    float b0 = weight_b[0], b1 = weight_b[1], b2 = weight_b[2];
    float m = fmaxf(b0, fmaxf(b1, b2));
    float e0 = expf(b0 - m), e1 = expf(b1 - m), e2 = expf(b2 - m);
    float s = e0 + e1 + e2;
    float pi0[3] = {e0 / s, e1 / s, e2 / s};
    float pi[3] = {pi0[0], pi0[1], pi0[2]};
    for (int it = 0; it < 13; ++it) {
        float n0 = pi[0] * T[0][0] + pi[1] * T[1][0] + pi[2] * T[2][0];
        float n1 = pi[0] * T[0][1] + pi[1] * T[1][1] + pi[2] * T[2][1];
        float n2 = pi[0] * T[0][2] + pi[1] * T[1][2] + pi[2] * T[2][2];
        pi[0] = 0.2f * pi0[0] + 0.8f * n0;
        pi[1] = 0.2f * pi0[1] + 0.8f * n1;
        pi[2] = 0.2f * pi0[2] + 0.8f * n2;
    }
    wout[0] = pi[0]; wout[1] = pi[1]; wout[2] = pi[2];
    float mm = fmaxf(pi[0], fmaxf(pi[1], pi[2]));
    float f0 = expf(pi[0] - mm), f1 = expf(pi[1] - mm), f2 = expf(pi[2] - mm);
    float fs = f0 + f1 + f2;
    wout[3] = f0 / fs; wout[4] = f1 / fs; wout[5] = f2 / fs;
}

__global__ void hraw_final(const float* __restrict__ U1, float* __restrict__ Hraw) {
    long i = (long)blockIdx.x * blockDim.x + threadIdx.x;
    if (i >= (long)NN * OUTD) return;
    Hraw[i] = 0.5f * (U1[i] + Hraw[i]);
}

extern "C" void kernel_launch(void* const* d_in, const int* in_sizes, int n_in,
                              void* d_out, int out_size, void* d_ws, size_t ws_size,
                              hipStream_t stream) {
    const float* feature   = (const float*)d_in[0];
    const int*   edge_index= (const int*)d_in[1];
    const float* edge_val  = (const float*)d_in[2];
    const float* spec_w1   = (const float*)d_in[3];
    const float* spec_b1   = (const float*)d_in[4];
    const float* spec_w2   = (const float*)d_in[5];
    const float* spec_b2   = (const float*)d_in[6];
    const float* shared_w1 = (const float*)d_in[7];
    const float* shared_b1 = (const float*)d_in[8];
    const float* shared_w2 = (const float*)d_in[9];
    const float* shared_b2 = (const float*)d_in[10];
    const float* weight_b  = (const float*)d_in[11];
    const float* tau       = (const float*)d_in[12];
    const float* mlp_w1    = (const float*)d_in[13];
    const float* mlp_b1    = (const float*)d_in[14];
    const float* mlp_w2    = (const float*)d_in[15];
    const float* mlp_b2    = (const float*)d_in[16];
    const float* raw_w1    = (const float*)d_in[17];
    const float* raw_b1    = (const float*)d_in[18];
    const float* raw_w2    = (const float*)d_in[19];
    const float* raw_b2    = (const float*)d_in[20];
    const float* proj_w    = (const float*)d_in[21];
    const float* proj_b    = (const float*)d_in[22];

    float* out        = (float*)d_out;
    float* spec_stack = out + (long)NN * OUTD;
    float* shr_stack  = spec_stack + 3L * NN * OUTD;
    float* Hcol       = out + 7L * NN * OUTD;
    float* Hraw       = out + 8L * NN * OUTD;

    // ---- workspace carve ----
    char* wp = (char*)d_ws;
    float* bufXW = (float*)wp; wp += (long)NN * 128 * sizeof(float);
    float* bufH1 = (float*)wp; wp += (long)NN * 128 * sizeof(float);
    float* bufB  = (float*)wp; wp += (long)NN * OUTD * sizeof(float);
    float* bufU1 = (float*)wp; wp += (long)NN * OUTD * sizeof(float);
    float* psBuf = (float*)wp; wp += 1024 * sizeof(float);
    float* wBuf  = (float*)wp; wp += 64 * sizeof(float);
    float* zBuf  = (float*)wp; wp += 256 * sizeof(float);
    float* pMax  = (float*)wp; wp += (long)3 * 64 * NCH * sizeof(float);
    float* pSum  = (float*)wp; wp += (long)3 * 64 * NCH * sizeof(float);
    float* pExp  = (float*)wp; wp += (long)3 * 64 * NCH * sizeof(float);
    float* pEnt  = (float*)wp; wp += (long)3 * 64 * NCH * sizeof(float);
    int*   csr_col[NP]; float* csr_val[NP]; int* rowptr[NP];
    for (int p = 0; p < NP; ++p) {
        csr_col[p] = (int*)wp;   wp += (long)NE * sizeof(int);
        csr_val[p] = (float*)wp; wp += (long)NE * sizeof(float);
        rowptr[p]  = (int*)wp;   wp += (NN + 2) * sizeof(int);
    }
    int* cnt    = (int*)wp; wp += (long)NN * sizeof(int);
    int* cursor = (int*)wp; wp += (long)NN * sizeof(int);

    const int TB = 256;
    int g_edges = cdiv(NE, TB);
    int g_rows = cdiv(NN, 64);  // 782

    // ---- build CSR for each plane ----
    for (int p = 0; p < NP; ++p) {
        const int* rows = edge_index + ((long)p * 2 + 0) * NE;
        const int* cols = edge_index + ((long)p * 2 + 1) * NE;
        const float* vals = edge_val + (long)p * NE;
        hipMemsetAsync(cnt, 0, NN * sizeof(int), stream);
        hist_rows<<<g_edges, TB, 0, stream>>>(rows, cnt);
        scan_rowptr<<<1, 1024, 0, stream>>>(cnt, rowptr[p]);
        hipMemcpyAsync(cursor, rowptr[p], NN * sizeof(int), hipMemcpyDeviceToDevice, stream);
        scatter_edges<<<g_edges, TB, 0, stream>>>(rows, cols, vals, cursor, csr_col[p], csr_val[p]);
    }

    // ---- specific planes ----
    for (int p = 0; p < NP; ++p) {
        gemm_tiled<256, 128, 0, 0><<<g_rows, 256, 0, stream>>>(
            feature, spec_w1 + (long)p * 256 * 128, nullptr, bufXW, NN, nullptr, nullptr, nullptr, nullptr);
        spmm_csr<128, 1><<<NN, 128, 0, stream>>>(rowptr[p], csr_col[p], csr_val[p], bufXW,
                                                 spec_b1 + (long)p * 128, bufH1);
        gemm_tiled<128, 64, 0, 0><<<g_rows, 256, 0, stream>>>(
            bufH1, spec_w2 + (long)p * 128 * 64, nullptr, bufB, NN, nullptr, nullptr, nullptr, nullptr);
        spmm_csr<64, 0><<<NN, 64, 0, stream>>>(rowptr[p], csr_col[p], csr_val[p], bufB,
                                               spec_b2 + (long)p * 64, spec_stack + (long)p * NN * OUTD);
    }

    // ---- shared planes (XW computed once) ----
    gemm_tiled<256, 128, 0, 0><<<g_rows, 256, 0, stream>>>(
        feature, shared_w1, nullptr, bufXW, NN, nullptr, nullptr, nullptr, nullptr);
    for (int p = 0; p < NP; ++p) {
        spmm_csr<128, 1><<<NN, 128, 0, stream>>>(rowptr[p], csr_col[p], csr_val[p], bufXW,
                                                 shared_b1, bufH1);
        gemm_tiled<128, 64, 0, 0><<<g_rows, 256, 0, stream>>>(
            bufH1, shared_w2, nullptr, bufB, NN, nullptr, nullptr, nullptr, nullptr);
        spmm_csr<64, 0><<<NN, 64, 0, stream>>>(rowptr[p], csr_col[p], csr_val[p], bufB,
                                               shared_b2, shr_stack + (long)p * NN * OUTD);
    }

    // ---- summaries + random walk ----
    {
        dim3 gA(NCH, 3);
        colsum_passA<<<gA, 256, 0, stream>>>(spec_stack, pMax, pSum, pExp);
        colsum_reduceB<<<192, 64, 0, stream>>>(pMax, pSum, pExp, psBuf, zBuf);
        colsum_passC<<<gA, 256, 0, stream>>>(spec_stack, psBuf, zBuf, pEnt);
        colsum_reduceD<<<192, 64, 0, stream>>>(pEnt, psBuf);
    }
    walk_kernel<<<1, 64, 0, stream>>>(psBuf, weight_b, tau, wBuf);

    // ---- H_col ----
    gemm_tiled<192, 128, 1, 2><<<g_rows, 256, 0, stream>>>(
        spec_stack, mlp_w1, mlp_b1, bufXW, NN, nullptr, nullptr, nullptr, nullptr);
    gemm_tiled<128, 64, 0, 0><<<g_rows, 256, 0, stream>>>(
        bufXW, mlp_w2, mlp_b2, Hcol, NN, nullptr, nullptr, nullptr, nullptr);

    // ---- H_raw ----
    gemm_tiled<256, 64, 0, 0><<<g_rows, 256, 0, stream>>>(
        feature, raw_w1, nullptr, bufB, NN, nullptr, nullptr, nullptr, nullptr);
    spmm_csr_merged<<<NN, 64, 0, stream>>>(rowptr[0], csr_col[0], csr_val[0],
                                           rowptr[1], csr_col[1], csr_val[1],
                                           rowptr[2], csr_col[2], csr_val[2],
                                           bufB, wBuf, raw_b1, bufU1);
    gemm_tiled<64, 64, 0, 0><<<g_rows, 256, 0, stream>>>(
        bufU1, raw_w2, nullptr, bufB, NN, nullptr, nullptr, nullptr, nullptr);
    spmm_csr_merged<<<NN, 64, 0, stream>>>(rowptr[0], csr_col[0], csr_val[0],
                                           rowptr[1], csr_col[1], csr_val[1],
                                           rowptr[2], csr_col[2], csr_val[2],
                                           bufB, wBuf, raw_b2, Hraw);
    hraw_final<<<cdiv((long)NN * OUTD, TB), TB, 0, stream>>>(bufU1, Hraw);

    // ---- final projection (mix fused into A-loader) ----
    gemm_tiled<256, 64, 2, 0><<<g_rows, 256, 0, stream>>>(
        spec_stack, proj_w, proj_b, out, NN, wBuf, shr_stack, Hcol, Hraw);
}

// Round 4
// 2100.118 us; speedup vs baseline: 3.0179x; 1.3294x over previous
//
#include <hip/hip_runtime.h>
#include <hip/hip_bf16.h>
#include <math.h>

#define NN 50000
#define NFEAT 256
#define NHID 128
#define OUTD 64
#define NE 800000
#define NP 3
#define NCH 64
#define RC 782  // ceil(NN/NCH)

typedef __hip_bfloat16 bf16;

static inline int cdiv(long a, long b) { return (int)((a + b - 1) / b); }

__device__ __forceinline__ void store_val(float v, float* p) { *p = v; }
__device__ __forceinline__ void store_val(float v, bf16* p) { *p = __float2bfloat16(v); }

// =============== tiled f32 GEMM ===============
// BM=64 rows/block, BK=32, BN=M. 256 threads, thread tile 4 x TN (TN=M/16).
// MODE: 0 plain A[n*K+k] ; 1 concat3 (A=spec_stack, K=192) ; 2 mix (final all_feat, K=256)
// ACT: 0 none, 2 relu.  OT: output type (float or bf16)
template <int K, int M, int MODE, int ACT, typename OT>
__global__ __launch_bounds__(256) void gemm_tiled(
    const float* __restrict__ A, const float* __restrict__ B,
    const float* __restrict__ bias, OT* __restrict__ out, int nrows,
    const float* __restrict__ wvec, const float* __restrict__ s1,
    const float* __restrict__ s2, const float* __restrict__ s3) {
    constexpr int TN = M / 16;
    constexpr int APAD = 68;
    __shared__ float As[32 * APAD];     // As[k][row]
    __shared__ float Bs[32 * M];        // Bs[k][col]

    int n0 = blockIdx.x * 64;
    int t = threadIdx.x;
    int tx = t & 15, ty = t >> 4;
    int col0 = tx * TN, row0 = ty * 4;

    float w0 = 0.f, w1 = 0.f, w2 = 0.f;
    if (MODE == 2) { w0 = wvec[3]; w1 = wvec[4]; w2 = wvec[5]; }

    float acc[4][TN];
#pragma unroll
    for (int i = 0; i < 4; ++i)
#pragma unroll
        for (int j = 0; j < TN; ++j) acc[i][j] = 0.f;

    int kk = t & 31, rr = t >> 5;

    for (int k0 = 0; k0 < K; k0 += 32) {
#pragma unroll
        for (int pass = 0; pass < 8; ++pass) {
            int row = rr + pass * 8;
            int gn = n0 + row;
            float v = 0.f;
            if (gn < nrows) {
                if (MODE == 0) {
                    v = A[(long)gn * K + k0 + kk];
                } else if (MODE == 1) {
                    int plane = k0 >> 6;
                    int d = (k0 & 63) + kk;
                    v = A[((long)plane * NN + gn) * OUTD + d];
                } else {
                    int seg = k0 >> 6;
                    int d = (k0 & 63) + kk;
                    if (seg == 0) {
                        v = w0 * A[((long)0 * NN + gn) * OUTD + d] +
                            w1 * A[((long)1 * NN + gn) * OUTD + d] +
                            w2 * A[((long)2 * NN + gn) * OUTD + d];
                    } else if (seg == 1) {
                        v = (s1[((long)0 * NN + gn) * OUTD + d] +
                             s1[((long)1 * NN + gn) * OUTD + d] +
                             s1[((long)2 * NN + gn) * OUTD + d]) * (1.0f / 3.0f);
                    } else if (seg == 2) {
                        v = s2[(long)gn * OUTD + d];
                    } else {
                        v = s3[(long)gn * OUTD + d];
                    }
                }
            }
            As[kk * APAD + row] = v;
        }
#pragma unroll
        for (int i = 0; i < (32 * M) / 256; ++i) {
            int idx = i * 256 + t;
            int kr = idx / M, col = idx % M;
            Bs[kr * M + col] = B[(long)(k0 + kr) * M + col];
        }
        __syncthreads();
#pragma unroll 8
        for (int k = 0; k < 32; ++k) {
            float ra[4], rb[TN];
#pragma unroll
            for (int i = 0; i < 4; ++i) ra[i] = As[k * APAD + row0 + i];
#pragma unroll
            for (int j = 0; j < TN; ++j) rb[j] = Bs[k * M + col0 + j];
#pragma unroll
            for (int i = 0; i < 4; ++i)
#pragma unroll
                for (int j = 0; j < TN; ++j) acc[i][j] += ra[i] * rb[j];
        }
        __syncthreads();
    }
#pragma unroll
    for (int i = 0; i < 4; ++i) {
        int gn = n0 + row0 + i;
        if (gn >= nrows) continue;
#pragma unroll
        for (int j = 0; j < TN; ++j) {
            float v = acc[i][j] + (bias ? bias[col0 + j] : 0.f);
            if (ACT == 2) v = fmaxf(v, 0.f);
            store_val(v, &out[(long)gn * M + col0 + j]);
        }
    }
}

// =============== CSR build ===============
__global__ void hist_rows(const int* __restrict__ rows, int* __restrict__ cnt) {
    int e = blockIdx.x * blockDim.x + threadIdx.x;
    if (e >= NE) return;
    atomicAdd(&cnt[rows[e]], 1);
}

__global__ void scan_rowptr(const int* __restrict__ cnt, int* __restrict__ rowptr) {
    __shared__ int partial[1024];
    const int CH = (NN + 1023) / 1024;
    int t = threadIdx.x;
    int base = t * CH;
    int s = 0;
    for (int i = 0; i < CH; ++i) {
        int idx = base + i;
        if (idx < NN) s += cnt[idx];
    }
    partial[t] = s;
    __syncthreads();
    for (int off = 1; off < 1024; off <<= 1) {
        int v = 0;
        if (t >= off) v = partial[t - off];
        __syncthreads();
        if (t >= off) partial[t] += v;
        __syncthreads();
    }
    int run = (t == 0) ? 0 : partial[t - 1];
    for (int i = 0; i < CH; ++i) {
        int idx = base + i;
        if (idx < NN) { rowptr[idx] = run; run += cnt[idx]; }
    }
    if (t == 0) rowptr[NN] = partial[1023];
}

__global__ void scatter_edges(const int* __restrict__ rows, const int* __restrict__ cols,
                              const float* __restrict__ vals, int* __restrict__ cursor,
                              int* __restrict__ csr_col, float* __restrict__ csr_val) {
    int e = blockIdx.x * blockDim.x + threadIdx.x;
    if (e >= NE) return;
    int r = rows[e];
    int pos = atomicAdd(&cursor[r], 1);
    csr_col[pos] = cols[e];
    csr_val[pos] = vals[e];
}

// =============== fused dual gather SpMM (bf16 Y) ===============
// outA[n,t] = act( spmm(Ya)[n,t] + biasA[t] ), same for B. One pass over edges.
template <int M, int ACT>  // ACT: 0 none, 1 telu
__global__ void spmm_dual(const int* __restrict__ rowptr, const int* __restrict__ ccol,
                          const float* __restrict__ cval,
                          const bf16* __restrict__ Ya, const bf16* __restrict__ Yb,
                          const float* __restrict__ biasA, const float* __restrict__ biasB,
                          float* __restrict__ outA, float* __restrict__ outB) {
    int n = blockIdx.x, t = threadIdx.x;
    int e0 = rowptr[n], e1 = rowptr[n + 1];
    float accA = biasA[t], accB = biasB[t];
    int e = e0;
    for (; e + 3 < e1; e += 4) {
        int c0 = ccol[e], c1 = ccol[e + 1], c2 = ccol[e + 2], c3 = ccol[e + 3];
        float v0 = cval[e], v1 = cval[e + 1], v2 = cval[e + 2], v3 = cval[e + 3];
        float a0 = __bfloat162float(Ya[(long)c0 * M + t]);
        float a1 = __bfloat162float(Ya[(long)c1 * M + t]);
        float a2 = __bfloat162float(Ya[(long)c2 * M + t]);
        float a3 = __bfloat162float(Ya[(long)c3 * M + t]);
        float b0 = __bfloat162float(Yb[(long)c0 * M + t]);
        float b1 = __bfloat162float(Yb[(long)c1 * M + t]);
        float b2 = __bfloat162float(Yb[(long)c2 * M + t]);
        float b3 = __bfloat162float(Yb[(long)c3 * M + t]);
        accA += v0 * a0 + v1 * a1 + v2 * a2 + v3 * a3;
        accB += v0 * b0 + v1 * b1 + v2 * b2 + v3 * b3;
    }
    for (; e < e1; ++e) {
        int c = ccol[e];
        float v = cval[e];
        accA += v * __bfloat162float(Ya[(long)c * M + t]);
        accB += v * __bfloat162float(Yb[(long)c * M + t]);
    }
    if (ACT == 1) { accA = accA * tanhf(expf(accA)); accB = accB * tanhf(expf(accB)); }
    outA[(long)n * M + t] = accA;
    outB[(long)n * M + t] = accB;
}

// merged 3-plane spmm (bf16 Y): out[n,t] = sum_p w[p]*spmm_p(Y)[n,t] + bias[t]
__global__ void spmm_merged(const int* __restrict__ rp0, const int* __restrict__ cc0, const float* __restrict__ cv0,
                            const int* __restrict__ rp1, const int* __restrict__ cc1, const float* __restrict__ cv1,
                            const int* __restrict__ rp2, const int* __restrict__ cc2, const float* __restrict__ cv2,
                            const bf16* __restrict__ Y, const float* __restrict__ wvec,
                            const float* __restrict__ bias, float* __restrict__ out) {
    int n = blockIdx.x, t = threadIdx.x;  // 64 threads
    const int* rps[3] = {rp0, rp1, rp2};
    const int* ccs[3] = {cc0, cc1, cc2};
    const float* cvs[3] = {cv0, cv1, cv2};
    float acc = 0.0f;
#pragma unroll
    for (int p = 0; p < 3; ++p) {
        const int* cc = ccs[p];
        const float* cv = cvs[p];
        int e0 = rps[p][n], e1 = rps[p][n + 1];
        float a = 0.f;
        int e = e0;
        for (; e + 3 < e1; e += 4) {
            int c0 = cc[e], c1 = cc[e + 1], c2 = cc[e + 2], c3 = cc[e + 3];
            float v0 = cv[e], v1 = cv[e + 1], v2 = cv[e + 2], v3 = cv[e + 3];
            a += v0 * __bfloat162float(Y[(long)c0 * OUTD + t]) +
                 v1 * __bfloat162float(Y[(long)c1 * OUTD + t]) +
                 v2 * __bfloat162float(Y[(long)c2 * OUTD + t]) +
                 v3 * __bfloat162float(Y[(long)c3 * OUTD + t]);
        }
        for (; e < e1; ++e) a += cv[e] * __bfloat162float(Y[(long)cc[e] * OUTD + t]);
        acc += wvec[p] * a;
    }
    out[(long)n * OUTD + t] = acc + bias[t];
}

// =============== column summaries (coalesced, chunked) ===============
__global__ void colsum_passA(const float* __restrict__ spec, float* __restrict__ pmax,
                             float* __restrict__ psum, float* __restrict__ pexp) {
    int p = blockIdx.y, c = blockIdx.x;
    int t = threadIdx.x;
    int d = t & 63, rg = t >> 6;
    const float* base = spec + (long)p * NN * OUTD;
    int r0 = c * RC, r1 = min(r0 + RC, NN);
    float m = -INFINITY, s = 0.f, e = 0.f;
    for (int r = r0 + rg; r < r1; r += 4) {
        float v = base[(long)r * OUTD + d];
        s += v;
        if (v > m) { e = e * __expf(m - v) + 1.0f; m = v; }
        else e += __expf(v - m);
    }
    __shared__ float rm[256], rs[256], re[256];
    rm[t] = m; rs[t] = s; re[t] = e;
    __syncthreads();
    for (int off = 128; off >= 64; off >>= 1) {
        if (t < off) {
            float m2 = fmaxf(rm[t], rm[t + off]);
            re[t] = re[t] * __expf(rm[t] - m2) + re[t + off] * __expf(rm[t + off] - m2);
            rm[t] = m2;
            rs[t] = rs[t] + rs[t + off];
        }
        __syncthreads();
    }
    if (t < 64) {
        long idx = ((long)p * 64 + t) * NCH + c;
        pmax[idx] = rm[t]; psum[idx] = rs[t]; pexp[idx] = re[t];
    }
}

__global__ void colsum_reduceB(const float* __restrict__ pmax, const float* __restrict__ psum,
                               const float* __restrict__ pexp, float* __restrict__ ps,
                               float* __restrict__ zbuf) {
    int b = blockIdx.x;
    int p = b >> 6, d = b & 63;
    int t = threadIdx.x;
    long idx = (long)b * NCH + t;
    float m = pmax[idx], s = psum[idx], e = pexp[idx];
    for (int off = 32; off > 0; off >>= 1) {
        float m2 = fmaxf(m, __shfl_xor(m, off));
        e = e * __expf(m - m2) + __shfl_xor(e, off) * __expf(__shfl_xor(m, off) - m2);
        m = m2;
        s += __shfl_xor(s, off);
    }
    if (t == 0) {
        ps[p * 192 + d] = s / (float)NN;
        ps[p * 192 + 64 + d] = m;
        zbuf[b] = e;
    }
}

__global__ void colsum_passC(const float* __restrict__ spec, const float* __restrict__ ps,
                             const float* __restrict__ zbuf, float* __restrict__ pent) {
    int p = blockIdx.y, c = blockIdx.x;
    int t = threadIdx.x;
    int d = t & 63, rg = t >> 6;
    const float* base = spec + (long)p * NN * OUTD;
    float gm = ps[p * 192 + 64 + d];
    float zinv = 1.0f / zbuf[p * 64 + d];
    int r0 = c * RC, r1 = min(r0 + RC, NN);
    float ent = 0.f;
    for (int r = r0 + rg; r < r1; r += 4) {
        float v = base[(long)r * OUTD + d];
        float pv = __expf(v - gm) * zinv;
        ent -= pv * __logf(pv + 1e-6f);
    }
    __shared__ float rd[256];
    rd[t] = ent;
    __syncthreads();
    for (int off = 128; off >= 64; off >>= 1) {
        if (t < off) rd[t] += rd[t + off];
        __syncthreads();
    }
    if (t < 64) pent[((long)p * 64 + t) * NCH + c] = rd[t];
}

__global__ void colsum_reduceD(const float* __restrict__ pent, float* __restrict__ ps) {
    int b = blockIdx.x;
    int p = b >> 6, d = b & 63;
    int t = threadIdx.x;
    float e = pent[(long)b * NCH + t];
    for (int off = 32; off > 0; off >>= 1) e += __shfl_xor(e, off);
    if (t == 0) ps[p * 192 + 128 + d] = e;
}

// =============== walk + epilogue ===============
__global__ void walk_kernel(const float* __restrict__ ps, const float* __restrict__ weight_b,
                            const float* __restrict__ tau_p, float* __restrict__ wout) {
    if (threadIdx.x != 0 || blockIdx.x != 0) return;
    float sim[3][3];
    float inv = 1.0f / (sqrtf(192.0f) * tau_p[0]);
    for (int i = 0; i < 3; ++i)
        for (int j = 0; j < 3; ++j) {
            float dotv = 0.f;
            for (int k = 0; k < 192; ++k) dotv += ps[i * 192 + k] * ps[j * 192 + k];
            sim[i][j] = dotv * inv;
        }
    float T[3][3];
    for (int i = 0; i < 3; ++i) {
        float m = fmaxf(sim[i][0], fmaxf(sim[i][1], sim[i][2]));
        float e0 = expf(sim[i][0] - m), e1 = expf(sim[i][1] - m), e2 = expf(sim[i][2] - m);
        float s = e0 + e1 + e2;
        T[i][0] = e0 / s; T[i][1] = e1 / s; T[i][2] = e2 / s;
    }
    float b0 = weight_b[0], b1 = weight_b[1], b2 = weight_b[2];
    float m = fmaxf(b0, fmaxf(b1, b2));
    float e0 = expf(b0 - m), e1 = expf(b1 - m), e2 = expf(b2 - m);
    float s = e0 + e1 + e2;
    float pi0[3] = {e0 / s, e1 / s, e2 / s};
    float pi[3] = {pi0[0], pi0[1], pi0[2]};
    for (int it = 0; it < 13; ++it) {
        float n0 = pi[0] * T[0][0] + pi[1] * T[1][0] + pi[2] * T[2][0];
        float n1 = pi[0] * T[0][1] + pi[1] * T[1][1] + pi[2] * T[2][1];
        float n2 = pi[0] * T[0][2] + pi[1] * T[1][2] + pi[2] * T[2][2];
        pi[0] = 0.2f * pi0[0] + 0.8f * n0;
        pi[1] = 0.2f * pi0[1] + 0.8f * n1;
        pi[2] = 0.2f * pi0[2] + 0.8f * n2;
    }
    wout[0] = pi[0]; wout[1] = pi[1]; wout[2] = pi[2];
    float mm = fmaxf(pi[0], fmaxf(pi[1], pi[2]));
    float f0 = expf(pi[0] - mm), f1 = expf(pi[1] - mm), f2 = expf(pi[2] - mm);
    float fs = f0 + f1 + f2;
    wout[3] = f0 / fs; wout[4] = f1 / fs; wout[5] = f2 / fs;
}

__global__ void hraw_final(const float* __restrict__ U1, float* __restrict__ Hraw) {
    long i = (long)blockIdx.x * blockDim.x + threadIdx.x;
    if (i >= (long)NN * OUTD) return;
    Hraw[i] = 0.5f * (U1[i] + Hraw[i]);
}

extern "C" void kernel_launch(void* const* d_in, const int* in_sizes, int n_in,
                              void* d_out, int out_size, void* d_ws, size_t ws_size,
                              hipStream_t stream) {
    const float* feature   = (const float*)d_in[0];
    const int*   edge_index= (const int*)d_in[1];
    const float* edge_val  = (const float*)d_in[2];
    const float* spec_w1   = (const float*)d_in[3];
    const float* spec_b1   = (const float*)d_in[4];
    const float* spec_w2   = (const float*)d_in[5];
    const float* spec_b2   = (const float*)d_in[6];
    const float* shared_w1 = (const float*)d_in[7];
    const float* shared_b1 = (const float*)d_in[8];
    const float* shared_w2 = (const float*)d_in[9];
    const float* shared_b2 = (const float*)d_in[10];
    const float* weight_b  = (const float*)d_in[11];
    const float* tau       = (const float*)d_in[12];
    const float* mlp_w1    = (const float*)d_in[13];
    const float* mlp_b1    = (const float*)d_in[14];
    const float* mlp_w2    = (const float*)d_in[15];
    const float* mlp_b2    = (const float*)d_in[16];
    const float* raw_w1    = (const float*)d_in[17];
    const float* raw_b1    = (const float*)d_in[18];
    const float* raw_w2    = (const float*)d_in[19];
    const float* raw_b2    = (const float*)d_in[20];
    const float* proj_w    = (const float*)d_in[21];
    const float* proj_b    = (const float*)d_in[22];

    float* out        = (float*)d_out;
    float* spec_stack = out + (long)NN * OUTD;
    float* shr_stack  = spec_stack + 3L * NN * OUTD;
    float* Hcol       = out + 7L * NN * OUTD;
    float* Hraw       = out + 8L * NN * OUTD;

    // ---- workspace carve ----
    char* wp = (char*)d_ws;
    bf16* XWsh = (bf16*)wp; wp += (long)NN * 128 * sizeof(bf16);   // shared layer-1 Y
    bf16* XWsp = (bf16*)wp; wp += (long)NN * 128 * sizeof(bf16);   // spec layer-1 Y (per plane, reused)
    float* h1sp = (float*)wp; wp += (long)NN * 128 * sizeof(float); // also Hcol hidden
    float* h1sh = (float*)wp; wp += (long)NN * 128 * sizeof(float); // also U1 (Hraw phase)
    bf16* Bsp  = (bf16*)wp; wp += (long)NN * OUTD * sizeof(bf16);  // also RB1
    bf16* Bsh  = (bf16*)wp; wp += (long)NN * OUTD * sizeof(bf16);  // also RB2
    float* psBuf = (float*)wp; wp += 1024 * sizeof(float);
    float* wBuf  = (float*)wp; wp += 64 * sizeof(float);
    float* zBuf  = (float*)wp; wp += 256 * sizeof(float);
    float* pMax  = (float*)wp; wp += (long)3 * 64 * NCH * sizeof(float);
    float* pSum  = (float*)wp; wp += (long)3 * 64 * NCH * sizeof(float);
    float* pExp  = (float*)wp; wp += (long)3 * 64 * NCH * sizeof(float);
    float* pEnt  = (float*)wp; wp += (long)3 * 64 * NCH * sizeof(float);
    int*   csr_col[NP]; float* csr_val[NP]; int* rowptr[NP];
    for (int p = 0; p < NP; ++p) {
        csr_col[p] = (int*)wp;   wp += (long)NE * sizeof(int);
        csr_val[p] = (float*)wp; wp += (long)NE * sizeof(float);
        rowptr[p]  = (int*)wp;   wp += (NN + 2) * sizeof(int);
    }
    int* cnt    = (int*)wp; wp += (long)NN * sizeof(int);
    int* cursor = (int*)wp; wp += (long)NN * sizeof(int);

    const int TB = 256;
    int g_edges = cdiv(NE, TB);
    int g_rows = cdiv(NN, 64);  // 782

    // ---- build CSR per plane ----
    for (int p = 0; p < NP; ++p) {
        const int* rows = edge_index + ((long)p * 2 + 0) * NE;
        const int* cols = edge_index + ((long)p * 2 + 1) * NE;
        const float* vals = edge_val + (long)p * NE;
        hipMemsetAsync(cnt, 0, NN * sizeof(int), stream);
        hist_rows<<<g_edges, TB, 0, stream>>>(rows, cnt);
        scan_rowptr<<<1, 1024, 0, stream>>>(cnt, rowptr[p]);
        hipMemcpyAsync(cursor, rowptr[p], NN * sizeof(int), hipMemcpyDeviceToDevice, stream);
        scatter_edges<<<g_edges, TB, 0, stream>>>(rows, cols, vals, cursor, csr_col[p], csr_val[p]);
    }

    // ---- shared layer-1 GEMM (once) ----
    gemm_tiled<256, 128, 0, 0, bf16><<<g_rows, 256, 0, stream>>>(
        feature, shared_w1, nullptr, XWsh, NN, nullptr, nullptr, nullptr, nullptr);

    // ---- per plane: fused spec+shared pipeline ----
    for (int p = 0; p < NP; ++p) {
        gemm_tiled<256, 128, 0, 0, bf16><<<g_rows, 256, 0, stream>>>(
            feature, spec_w1 + (long)p * 256 * 128, nullptr, XWsp, NN, nullptr, nullptr, nullptr, nullptr);
        spmm_dual<128, 1><<<NN, 128, 0, stream>>>(rowptr[p], csr_col[p], csr_val[p],
                                                  XWsp, XWsh,
                                                  spec_b1 + (long)p * 128, shared_b1,
                                                  h1sp, h1sh);
        gemm_tiled<128, 64, 0, 0, bf16><<<g_rows, 256, 0, stream>>>(
            h1sp, spec_w2 + (long)p * 128 * 64, nullptr, Bsp, NN, nullptr, nullptr, nullptr, nullptr);
        gemm_tiled<128, 64, 0, 0, bf16><<<g_rows, 256, 0, stream>>>(
            h1sh, shared_w2, nullptr, Bsh, NN, nullptr, nullptr, nullptr, nullptr);
        spmm_dual<64, 0><<<NN, 64, 0, stream>>>(rowptr[p], csr_col[p], csr_val[p],
                                                Bsp, Bsh,
                                                spec_b2 + (long)p * 64, shared_b2,
                                                spec_stack + (long)p * NN * OUTD,
                                                shr_stack + (long)p * NN * OUTD);
    }

    // ---- summaries + random walk ----
    {
        dim3 gA(NCH, 3);
        colsum_passA<<<gA, 256, 0, stream>>>(spec_stack, pMax, pSum, pExp);
        colsum_reduceB<<<192, 64, 0, stream>>>(pMax, pSum, pExp, psBuf, zBuf);
        colsum_passC<<<gA, 256, 0, stream>>>(spec_stack, psBuf, zBuf, pEnt);
        colsum_reduceD<<<192, 64, 0, stream>>>(pEnt, psBuf);
    }
    walk_kernel<<<1, 64, 0, stream>>>(psBuf, weight_b, tau, wBuf);

    // ---- H_col (hidden reuses h1sp) ----
    gemm_tiled<192, 128, 1, 2, float><<<g_rows, 256, 0, stream>>>(
        spec_stack, mlp_w1, mlp_b1, h1sp, NN, nullptr, nullptr, nullptr, nullptr);
    gemm_tiled<128, 64, 0, 0, float><<<g_rows, 256, 0, stream>>>(
        h1sp, mlp_w2, mlp_b2, Hcol, NN, nullptr, nullptr, nullptr, nullptr);

    // ---- H_raw (U1 reuses h1sh; RB1/RB2 reuse Bsp/Bsh) ----
    float* U1 = h1sh;
    gemm_tiled<256, 64, 0, 0, bf16><<<g_rows, 256, 0, stream>>>(
        feature, raw_w1, nullptr, Bsp, NN, nullptr, nullptr, nullptr, nullptr);
    spmm_merged<<<NN, 64, 0, stream>>>(rowptr[0], csr_col[0], csr_val[0],
                                       rowptr[1], csr_col[1], csr_val[1],
                                       rowptr[2], csr_col[2], csr_val[2],
                                       Bsp, wBuf, raw_b1, U1);
    gemm_tiled<64, 64, 0, 0, bf16><<<g_rows, 256, 0, stream>>>(
        U1, raw_w2, nullptr, Bsh, NN, nullptr, nullptr, nullptr, nullptr);
    spmm_merged<<<NN, 64, 0, stream>>>(rowptr[0], csr_col[0], csr_val[0],
                                       rowptr[1], csr_col[1], csr_val[1],
                                       rowptr[2], csr_col[2], csr_val[2],
                                       Bsh, wBuf, raw_b2, Hraw);
    hraw_final<<<cdiv((long)NN * OUTD, TB), TB, 0, stream>>>(U1, Hraw);

    // ---- final projection (mix fused into A-loader) ----
    gemm_tiled<256, 64, 2, 0, float><<<g_rows, 256, 0, stream>>>(
        spec_stack, proj_w, proj_b, out, NN, wBuf, shr_stack, Hcol, Hraw);
}